// Round 5
// baseline (261.571 us; speedup 1.0000x reference)
//
#include <hip/hip_runtime.h>

typedef float2 cplx;

constexpr float TWO_PI = 6.28318530717958647692f;

__device__ inline void cmac(float& ax, float& ay, cplx a, cplx b) {
    ax += a.x * b.x - a.y * b.y;
    ay += a.x * b.y + a.y * b.x;
}

// ---- K_pre: A, Bq, Cq, e1, e2, h (+ atomic mean/var partials of h) ----------
// segments: [A:65536][Bq:81920][Cq:81920][e1:65536][e2:81920][h:262144]
__global__ __launch_bounds__(256) void k_pre(
    const float* __restrict__ x, const float* __restrict__ fc0_w,
    const float* __restrict__ fc0_b,
    const float* __restrict__ p1r, const float* __restrict__ p1i,
    const float* __restrict__ p2r, const float* __restrict__ p2i,
    const float* __restrict__ resr, const float* __restrict__ resi,
    const float* __restrict__ t_grid, const float* __restrict__ x_grid,
    cplx* __restrict__ A, cplx* __restrict__ Bq, cplx* __restrict__ Cq,
    cplx* __restrict__ e1, cplx* __restrict__ e2,
    float* __restrict__ h, float* __restrict__ accH)
{
    int idx = blockIdx.x * 256 + threadIdx.x;
    float dty = x_grid[1] - x_grid[0];
    float dtx = t_grid[1] - t_grid[0];
    const int NA = 65536, NBQ = 81920, NCQ = 81920, NE1 = 65536, NE2 = 81920;
    if (idx < NA) {
        int p = idx & 3, k = (idx >> 2) & 15, i = (idx >> 6) & 15, o = idx >> 10;
        int kf = (o < 32) ? o : o - 64;
        float om = TWO_PI * (float)kf / (64.f * dty);
        float dr = -p1r[(i * 16 + k) * 4 + p], di = om - p1i[(i * 16 + k) * 4 + p];
        float inv = 1.f / (dr * dr + di * di);
        A[idx] = make_float2(dr * inv, -di * inv);
        return;
    }
    idx -= NA;
    if (idx < NBQ) {
        int q = idx % 5, k = (idx / 5) & 15, i = (idx / 80) & 15, xx = idx / 1280;
        int kf = (xx < 32) ? xx : xx - 64;
        float om = TWO_PI * (float)kf / (64.f * dtx);
        float dr = -p2r[(i * 16 + k) * 5 + q], di = om - p2i[(i * 16 + k) * 5 + q];
        float inv = 1.f / (dr * dr + di * di);
        Bq[idx] = make_float2(dr * inv, -di * inv);
        return;
    }
    idx -= NBQ;
    if (idx < NCQ) {
        int q = idx % 5, k = (idx / 5) & 15, i = (idx / 80) & 15, o = idx / 1280;
        int kf = (o < 32) ? o : o - 64;
        float om = TWO_PI * (float)kf / (64.f * dty);
        float cx = 0.f, cy = 0.f;
        for (int p = 0; p < 4; ++p) {
            float dr = -p1r[(i * 16 + k) * 4 + p], di = om - p1i[(i * 16 + k) * 4 + p];
            float inv = 1.f / (dr * dr + di * di);
            float axr = dr * inv, axi = -di * inv;
            float rr = resr[((i * 16 + k) * 4 + p) * 5 + q];
            float ri = resi[((i * 16 + k) * 4 + p) * 5 + q];
            cx += rr * axr - ri * axi;
            cy += rr * axi + ri * axr;
        }
        Cq[idx] = make_float2(cx, cy);
        return;
    }
    idx -= NCQ;
    if (idx < NE1) {
        int z = idx & 63, w = idx >> 6;
        float t = x_grid[z];
        float m = expf(p1r[w] * t);
        float sn, cs; sincosf(p1i[w] * t, &sn, &cs);
        e1[idx] = make_float2(m * cs, m * sn);
        return;
    }
    idx -= NE1;
    if (idx < NE2) {
        int xx = idx & 63, w = idx >> 6;
        float t = t_grid[xx];
        float m = expf(p2r[w] * t);
        float sn, cs; sincosf(p2i[w] * t, &sn, &cs);
        e2[idx] = make_float2(m * cs, m * sn);
        return;
    }
    idx -= NE2;
    {   // h = fc0(x,gx,gy) + wave-reduced mean/var partials
        int bc = idx >> 12, pix = idx & 4095;
        int b = bc >> 4, c = bc & 15;
        int z = pix >> 6, xx = pix & 63;
        const float inv63 = 1.f / 63.f;
        float v = fc0_w[c * 3] * x[b * 4096 + pix]
                + fc0_w[c * 3 + 1] * (z * inv63)
                + fc0_w[c * 3 + 2] * (xx * inv63) + fc0_b[c];
        h[idx] = v;
        float s = v, s2 = v * v;
        for (int m = 32; m; m >>= 1) {
            s  += __shfl_xor(s,  m, 64);
            s2 += __shfl_xor(s2, m, 64);
        }
        if ((threadIdx.x & 63) == 0) {
            atomicAdd(&accH[bc * 2],     s);
            atomicAdd(&accH[bc * 2 + 1], s2);
        }
    }
}

// ---- K_fftA: T1[p][j] = rstd*(sum_i h[i][j]*W^(pi) - 64*mean*(p==0)) --------
__global__ __launch_bounds__(256) void k_fftA(
    const float* __restrict__ h, const float* __restrict__ accH,
    cplx* __restrict__ T1)
{
    __shared__ cplx Ws[64];
    int bc = blockIdx.x >> 4, pc = blockIdx.x & 15;
    int tid = threadIdx.x;
    if (tid < 64) { float sn, cs; sincosf(-TWO_PI * tid / 64.f, &sn, &cs); Ws[tid] = make_float2(cs, sn); }
    __syncthreads();
    float mean = accH[bc * 2] * (1.f / 4096.f);
    float var  = accH[bc * 2 + 1] * (1.f / 4096.f) - mean * mean;
    float rstd = rsqrtf(var + 1e-5f);
    int j = tid & 63, pl = tid >> 6, p = pc * 4 + pl;
    const float* hb = h + bc * 4096 + j;
    float ax = 0.f, ay = 0.f;
    #pragma unroll 8
    for (int i = 0; i < 64; ++i) {
        float v = hb[i * 64];
        cplx w = Ws[(p * i) & 63];
        ax += v * w.x; ay += v * w.y;
    }
    if (p == 0) ax -= 64.f * mean;
    T1[bc * 4096 + p * 64 + j] = make_float2(ax * rstd, ay * rstd);
}

// ---- K2: fft-stage-B: alpha[p][q] = sum_j T1[p][j]*W^(q*j); also alphaT -----
__global__ __launch_bounds__(256) void k2_fftB(
    const cplx* __restrict__ T1, cplx* __restrict__ alpha, cplx* __restrict__ alphaT)
{
    __shared__ cplx T1s[256];
    __shared__ cplx Ws[64];
    int bc = blockIdx.x >> 4, pc = blockIdx.x & 15;
    int tid = threadIdx.x;
    if (tid < 64) { float sn, cs; sincosf(-TWO_PI * tid / 64.f, &sn, &cs); Ws[tid] = make_float2(cs, sn); }
    T1s[tid] = T1[bc * 4096 + pc * 256 + tid];
    __syncthreads();
    int q = tid & 63, pl = tid >> 6, p = pc * 4 + pl;
    float ax = 0.f, ay = 0.f;
    #pragma unroll 8
    for (int j = 0; j < 64; ++j) cmac(ax, ay, T1s[pl * 64 + j], Ws[(q * j) & 63]);
    cplx v = make_float2(ax, ay);
    alpha [bc * 4096 + p * 64 + q] = v;
    alphaT[(p * 64 + q) * 64 + bc] = v;
}

// ---- K3: fused G+r1 per (o,x): G[i][k]=sum_q Cq*Bq; r1[b,k]=sum_i a[b,i]*G --
__global__ __launch_bounds__(64) void k3_r1(
    const cplx* __restrict__ alphaT, const cplx* __restrict__ Cq,
    const cplx* __restrict__ Bq, cplx* __restrict__ r1)
{
    __shared__ cplx Cqs[1280], Bqs[1280], Gs[256], as[64];
    int ox = blockIdx.x; int o = ox >> 6, xx = ox & 63;
    int t = threadIdx.x;
    for (int m = 0; m < 20; ++m) {
        Cqs[m * 64 + t] = Cq[o * 1280 + m * 64 + t];
        Bqs[m * 64 + t] = Bq[xx * 1280 + m * 64 + t];
    }
    as[t] = alphaT[ox * 64 + t];
    __syncthreads();
    for (int m = 0; m < 4; ++m) {
        int e = m * 64 + t; int i = e >> 4, k = e & 15;
        float gx = 0.f, gy = 0.f;
        for (int q = 0; q < 5; ++q) cmac(gx, gy, Cqs[i * 80 + k * 5 + q], Bqs[i * 80 + k * 5 + q]);
        Gs[e] = make_float2(gx, gy);
    }
    __syncthreads();
    int b = t >> 4, k = t & 15;
    float ax = 0.f, ay = 0.f;
    for (int i = 0; i < 16; ++i) cmac(ax, ay, as[b * 16 + i], Gs[i * 16 + k]);
    r1[t * 4096 + ox] = make_float2(ax, ay);
}

// ---- K4: inner1[bi][o][k][q] = sum_x alpha[bi][o][x] * Bq[x][i][k][q] -------
__global__ __launch_bounds__(256) void k4_inner1(
    const cplx* __restrict__ alpha, const cplx* __restrict__ Bq,
    cplx* __restrict__ inner1)
{
    int idx = blockIdx.x * 256 + threadIdx.x;      // bi*5120 + o*80 + kq
    int kq = idx % 80; int r = idx / 80; int o = r & 63; int bi = r >> 6; int i = bi & 15;
    const cplx* arow = alpha + bi * 4096 + o * 64;
    const cplx* bcol = Bq + i * 80 + kq;
    float ax = 0.f, ay = 0.f;
    #pragma unroll 4
    for (int x = 0; x < 64; ++x) cmac(ax, ay, arow[x], bcol[x * 1280]);
    inner1[idx] = make_float2(ax, ay);
}

// ---- K5: r2[b][k][p][q] = sum_i res[i,k,p,q] * sum_o A[o,i,k,p]*inner1 ------
__global__ __launch_bounds__(64) void k5_r2(
    const cplx* __restrict__ A, const cplx* __restrict__ inner1,
    const float* __restrict__ resr, const float* __restrict__ resi,
    cplx* __restrict__ r2)
{
    int bk = blockIdx.x; int b = bk >> 4, k = bk & 15;
    int o = threadIdx.x;
    float accx[4][5] = {}, accy[4][5] = {};
    for (int i = 0; i < 16; ++i) {
        cplx a[4];
        for (int p = 0; p < 4; ++p) a[p] = A[((o * 16 + i) * 16 + k) * 4 + p];
        cplx in[5];
        for (int q = 0; q < 5; ++q) in[q] = inner1[(b * 16 + i) * 5120 + o * 80 + k * 5 + q];
        int rb = (i * 16 + k) * 20;
        for (int p = 0; p < 4; ++p)
            for (int q = 0; q < 5; ++q) {
                float tx = a[p].x * in[q].x - a[p].y * in[q].y;
                float ty = a[p].x * in[q].y + a[p].y * in[q].x;
                float rr = resr[rb + p * 5 + q], ri = resi[rb + p * 5 + q];
                accx[p][q] += rr * tx - ri * ty;
                accy[p][q] += rr * ty + ri * tx;
            }
    }
    for (int m = 32; m; m >>= 1)
        for (int p = 0; p < 4; ++p)
            for (int q = 0; q < 5; ++q) {
                accx[p][q] += __shfl_xor(accx[p][q], m, 64);
                accy[p][q] += __shfl_xor(accy[p][q], m, 64);
            }
    if (o == 0)
        for (int p = 0; p < 4; ++p)
            for (int q = 0; q < 5; ++q)
                r2[bk * 20 + p * 5 + q] = make_float2(accx[p][q], accy[p][q]);
}

// ---- K6: V[kb][i][bb][q][z] = sum_p r2[kb,bb,p,q]*e1[bb,i,p,z] --------------
__global__ __launch_bounds__(256) void k6_V(
    const cplx* __restrict__ r2, const cplx* __restrict__ e1, cplx* __restrict__ V)
{
    int idx = blockIdx.x * 256 + threadIdx.x;
    int z = idx & 63;
    int rest = idx >> 6;
    int q = rest % 5; rest /= 5;
    int bb = rest & 15; rest >>= 4;
    int i = rest & 15;
    int kb = rest >> 4;
    float vx = 0.f, vy = 0.f;
    for (int p = 0; p < 4; ++p)
        cmac(vx, vy, r2[((kb * 16 + bb) * 4 + p) * 5 + q],
                     e1[((bb * 16 + i) * 4 + p) * 64 + z]);
    V[idx] = make_float2(vx, vy);
}

// ---- K7: ifft-stage-A: T2[z][j] = sum_o r1[o][j]*Wp^(z*o) -------------------
__global__ __launch_bounds__(256) void k7_ifftA(
    const cplx* __restrict__ r1, cplx* __restrict__ T2)
{
    __shared__ cplx Ws[64];
    int bk = blockIdx.x >> 4, zc = blockIdx.x & 15;
    int tid = threadIdx.x;
    if (tid < 64) { float sn, cs; sincosf(TWO_PI * tid / 64.f, &sn, &cs); Ws[tid] = make_float2(cs, sn); }
    __syncthreads();
    int j = tid & 63, z = zc * 4 + (tid >> 6);
    const cplx* rr = r1 + bk * 4096 + j;
    float ax = 0.f, ay = 0.f;
    #pragma unroll 4
    for (int o = 0; o < 64; ++o) cmac(ax, ay, rr[o * 64], Ws[(z * o) & 63]);
    T2[bk * 4096 + z * 64 + j] = make_float2(ax, ay);
}

// ---- K8a: sp = ifftB(T2) + Re(V*e2) (no norm); atomic mean/var partials -----
__global__ __launch_bounds__(256) void k8a_sp(
    const cplx* __restrict__ T2, const cplx* __restrict__ V,
    const cplx* __restrict__ e2, float* __restrict__ sp, float* __restrict__ accS)
{
    __shared__ cplx Ws[64];
    int bc = blockIdx.x >> 4, zc = blockIdx.x & 15;
    int ch = bc & 15;
    int tid = threadIdx.x;
    if (tid < 64) { float sn, cs; sincosf(TWO_PI * tid / 64.f, &sn, &cs); Ws[tid] = make_float2(cs, sn); }
    __syncthreads();
    int lp = zc * 256 + tid;            // local pixel in this bc
    int z = lp >> 6, xx = lp & 63;      // z wave-uniform
    const cplx* trow = T2 + bc * 4096 + z * 64;
    const cplx* Vb   = V + bc * 5120;
    const cplx* eb   = e2 + ch * 320 + xx;
    float acc = 0.f;
    #pragma unroll 8
    for (int j = 0; j < 64; ++j) {
        cplx v = trow[j]; cplx w = Ws[(xx * j) & 63];
        acc += v.x * w.x - v.y * w.y;
    }
    #pragma unroll 4
    for (int bb = 0; bb < 16; ++bb)
        for (int q = 0; q < 5; ++q) {
            cplx vv = Vb[bb * 320 + q * 64 + z];     // wave-uniform broadcast
            cplx ee = eb[bb * 5120 + q * 64];        // lane-consecutive
            acc += vv.x * ee.x - vv.y * ee.y;
        }
    float val = acc * (1.f / 4096.f);
    sp[bc * 4096 + lp] = val;
    float s = val, s2 = val * val;
    for (int m = 32; m; m >>= 1) {
        s  += __shfl_xor(s,  m, 64);
        s2 += __shfl_xor(s2, m, 64);
    }
    if ((tid & 63) == 0) {
        atomicAdd(&accS[bc * 2],     s);
        atomicAdd(&accS[bc * 2 + 1], s2);
    }
}

// ---- K9: out = fc2( sin( fc1( inorm(sp) + w0*h + w0_b ) ) ) -----------------
__global__ __launch_bounds__(256) void k9_final(
    const float* __restrict__ sp, const float* __restrict__ accS,
    const float* __restrict__ h,
    const float* __restrict__ w0_w, const float* __restrict__ w0_b,
    const float* __restrict__ fc1_w, const float* __restrict__ fc1_b,
    const float* __restrict__ fc2_w, const float* __restrict__ fc2_b,
    float* __restrict__ out)
{
    __shared__ float w1s[128 * 16], b1s[128], w2s[128], w0s[256], w0bs[16];
    __shared__ float mvm[16], mvr[16];
    int tid = threadIdx.x;
    int b = blockIdx.x >> 4;            // 16 blocks per batch
    for (int t = 0; t < 8; ++t) w1s[t * 256 + tid] = fc1_w[t * 256 + tid];
    if (tid < 128) { b1s[tid] = fc1_b[tid]; w2s[tid] = fc2_w[tid]; }
    w0s[tid] = w0_w[tid & 255];
    if (tid < 16) {
        w0bs[tid] = w0_b[tid];
        float mean = accS[(b * 16 + tid) * 2] * (1.f / 4096.f);
        float var  = accS[(b * 16 + tid) * 2 + 1] * (1.f / 4096.f) - mean * mean;
        mvm[tid] = mean;
        mvr[tid] = rsqrtf(var + 1e-5f);
    }
    float b2 = fc2_b[0];
    __syncthreads();
    int pix = blockIdx.x * 256 + tid;    // 0..16383
    int rem = pix & 4095;
    float hv[16], tv[16];
    for (int c = 0; c < 16; ++c) {
        hv[c] = h[(b * 16 + c) * 4096 + rem];
        tv[c] = (sp[(b * 16 + c) * 4096 + rem] - mvm[c]) * mvr[c];
    }
    for (int k = 0; k < 16; ++k) {
        float a = w0bs[k];
        for (int c = 0; c < 16; ++c) a += w0s[k * 16 + c] * hv[c];
        tv[k] += a;
    }
    float acc = b2;
    for (int n = 0; n < 128; ++n) {
        float s1 = b1s[n];
        for (int k2 = 0; k2 < 16; ++k2) s1 += w1s[n * 16 + k2] * tv[k2];
        acc += w2s[n] * sinf(s1);
    }
    out[pix] = acc;
}

extern "C" void kernel_launch(void* const* d_in, const int* in_sizes, int n_in,
                              void* d_out, int out_size, void* d_ws, size_t ws_size,
                              hipStream_t stream)
{
    const float* x     = (const float*)d_in[0];
    const float* fc0_w = (const float*)d_in[1];
    const float* fc0_b = (const float*)d_in[2];
    const float* p1r   = (const float*)d_in[3];
    const float* p1i   = (const float*)d_in[4];
    const float* p2r   = (const float*)d_in[5];
    const float* p2i   = (const float*)d_in[6];
    const float* resr  = (const float*)d_in[7];
    const float* resi  = (const float*)d_in[8];
    const float* w0_w  = (const float*)d_in[9];
    const float* w0_b  = (const float*)d_in[10];
    const float* fc1_w = (const float*)d_in[11];
    const float* fc1_b = (const float*)d_in[12];
    const float* fc2_w = (const float*)d_in[13];
    const float* fc2_b = (const float*)d_in[14];
    const float* t_grid= (const float*)d_in[15];
    const float* x_grid= (const float*)d_in[16];
    float* out = (float*)d_out;

    float* ws = (float*)d_ws;
    size_t off = 0;
    float* h      = ws + off; off += 262144;            // (64,4096)
    cplx*  T1     = (cplx*)(ws + off); off += 524288;   // (64,4096) c
    cplx*  alpha  = (cplx*)(ws + off); off += 524288;   // [bi][o][x] c
    cplx*  alphaT = (cplx*)(ws + off); off += 524288;   // [ox][bi] c
    cplx*  A      = (cplx*)(ws + off); off += 131072;   // (64,16,16,4) c
    cplx*  Bq     = (cplx*)(ws + off); off += 163840;   // (64,16,16,5) c
    cplx*  Cq     = (cplx*)(ws + off); off += 163840;   // (64,16,16,5) c
    cplx*  e1     = (cplx*)(ws + off); off += 131072;   // (16,16,4,64) c
    cplx*  e2     = (cplx*)(ws + off); off += 163840;   // (16,16,5,64) c
    cplx*  r1     = (cplx*)(ws + off); off += 524288;   // [bk][o][x] c
    cplx*  inner1 = (cplx*)(ws + off); off += 655360;   // [bi][o][k][q] c
    cplx*  r2     = (cplx*)(ws + off); off += 2560;     // (4,16,4,5) c
    cplx*  V      = (cplx*)(ws + off); off += 655360;   // (4,16,16,5,64) c
    cplx*  T2     = (cplx*)(ws + off); off += 524288;   // [bk][z][j] c
    float* sp     = ws + off; off += 262144;
    float* accum  = ws + off; off += 256;               // accH[128] + accS[128]
    float* accH = accum, *accS = accum + 128;
    (void)ws_size; (void)n_in; (void)in_sizes; (void)out_size;

    hipMemsetAsync(accum, 0, 256 * sizeof(float), stream);

    k_pre<<<2496, 256, 0, stream>>>(x, fc0_w, fc0_b, p1r, p1i, p2r, p2i, resr, resi,
                                    t_grid, x_grid, A, Bq, Cq, e1, e2, h, accH);
    k_fftA<<<1024, 256, 0, stream>>>(h, accH, T1);
    k2_fftB<<<1024, 256, 0, stream>>>(T1, alpha, alphaT);
    k3_r1<<<4096, 64, 0, stream>>>(alphaT, Cq, Bq, r1);
    k4_inner1<<<1280, 256, 0, stream>>>(alpha, Bq, inner1);
    k5_r2<<<64, 64, 0, stream>>>(A, inner1, resr, resi, r2);
    k6_V<<<1280, 256, 0, stream>>>(r2, e1, V);
    k7_ifftA<<<1024, 256, 0, stream>>>(r1, T2);
    k8a_sp<<<1024, 256, 0, stream>>>(T2, V, e2, sp, accS);
    k9_final<<<64, 256, 0, stream>>>(sp, accS, h, w0_w, w0_b, fc1_w, fc1_b, fc2_w, fc2_b, out);
}

// Round 6
// 251.568 us; speedup vs baseline: 1.0398x; 1.0398x over previous
//
#include <hip/hip_runtime.h>

typedef float2 cplx;

constexpr float TWO_PI = 6.28318530717958647692f;

__device__ inline void cmac(float& ax, float& ay, cplx a, cplx b) {
    ax += a.x * b.x - a.y * b.y;
    ay += a.x * b.y + a.y * b.x;
}

// ---- K_pre: A, Bq, Cq, e1, e2, h (+ atomic mean/var partials of h) ----------
__global__ __launch_bounds__(256) void k_pre(
    const float* __restrict__ x, const float* __restrict__ fc0_w,
    const float* __restrict__ fc0_b,
    const float* __restrict__ p1r, const float* __restrict__ p1i,
    const float* __restrict__ p2r, const float* __restrict__ p2i,
    const float* __restrict__ resr, const float* __restrict__ resi,
    const float* __restrict__ t_grid, const float* __restrict__ x_grid,
    cplx* __restrict__ A, cplx* __restrict__ Bq, cplx* __restrict__ Cq,
    cplx* __restrict__ e1, cplx* __restrict__ e2,
    float* __restrict__ h, float* __restrict__ accH)
{
    int idx = blockIdx.x * 256 + threadIdx.x;
    float dty = x_grid[1] - x_grid[0];
    float dtx = t_grid[1] - t_grid[0];
    const int NA = 65536, NBQ = 81920, NCQ = 81920, NE1 = 65536, NE2 = 81920;
    if (idx < NA) {
        int p = idx & 3, k = (idx >> 2) & 15, i = (idx >> 6) & 15, o = idx >> 10;
        int kf = (o < 32) ? o : o - 64;
        float om = TWO_PI * (float)kf / (64.f * dty);
        float dr = -p1r[(i * 16 + k) * 4 + p], di = om - p1i[(i * 16 + k) * 4 + p];
        float inv = 1.f / (dr * dr + di * di);
        A[idx] = make_float2(dr * inv, -di * inv);
        return;
    }
    idx -= NA;
    if (idx < NBQ) {
        int q = idx % 5, k = (idx / 5) & 15, i = (idx / 80) & 15, xx = idx / 1280;
        int kf = (xx < 32) ? xx : xx - 64;
        float om = TWO_PI * (float)kf / (64.f * dtx);
        float dr = -p2r[(i * 16 + k) * 5 + q], di = om - p2i[(i * 16 + k) * 5 + q];
        float inv = 1.f / (dr * dr + di * di);
        Bq[idx] = make_float2(dr * inv, -di * inv);
        return;
    }
    idx -= NBQ;
    if (idx < NCQ) {
        int q = idx % 5, k = (idx / 5) & 15, i = (idx / 80) & 15, o = idx / 1280;
        int kf = (o < 32) ? o : o - 64;
        float om = TWO_PI * (float)kf / (64.f * dty);
        float cx = 0.f, cy = 0.f;
        for (int p = 0; p < 4; ++p) {
            float dr = -p1r[(i * 16 + k) * 4 + p], di = om - p1i[(i * 16 + k) * 4 + p];
            float inv = 1.f / (dr * dr + di * di);
            float axr = dr * inv, axi = -di * inv;
            float rr = resr[((i * 16 + k) * 4 + p) * 5 + q];
            float ri = resi[((i * 16 + k) * 4 + p) * 5 + q];
            cx += rr * axr - ri * axi;
            cy += rr * axi + ri * axr;
        }
        Cq[idx] = make_float2(cx, cy);
        return;
    }
    idx -= NCQ;
    if (idx < NE1) {
        int z = idx & 63, w = idx >> 6;
        float t = x_grid[z];
        float m = expf(p1r[w] * t);
        float sn, cs; sincosf(p1i[w] * t, &sn, &cs);
        e1[idx] = make_float2(m * cs, m * sn);
        return;
    }
    idx -= NE1;
    if (idx < NE2) {
        int xx = idx & 63, w = idx >> 6;
        float t = t_grid[xx];
        float m = expf(p2r[w] * t);
        float sn, cs; sincosf(p2i[w] * t, &sn, &cs);
        e2[idx] = make_float2(m * cs, m * sn);
        return;
    }
    idx -= NE2;
    {   // h = fc0(x,gx,gy) + wave-reduced mean/var partials
        int bc = idx >> 12, pix = idx & 4095;
        int b = bc >> 4, c = bc & 15;
        int z = pix >> 6, xx = pix & 63;
        const float inv63 = 1.f / 63.f;
        float v = fc0_w[c * 3] * x[b * 4096 + pix]
                + fc0_w[c * 3 + 1] * (z * inv63)
                + fc0_w[c * 3 + 2] * (xx * inv63) + fc0_b[c];
        h[idx] = v;
        float s = v, s2 = v * v;
        for (int m = 32; m; m >>= 1) {
            s  += __shfl_xor(s,  m, 64);
            s2 += __shfl_xor(s2, m, 64);
        }
        if ((threadIdx.x & 63) == 0) {
            atomicAdd(&accH[bc * 2],     s);
            atomicAdd(&accH[bc * 2 + 1], s2);
        }
    }
}

// ---- K_fftA: T1[p][j] = rstd*(sum_i h[i][j]*W^(pi) - 64*mean*(p==0)) --------
__global__ __launch_bounds__(256) void k_fftA(
    const float* __restrict__ h, const float* __restrict__ accH,
    cplx* __restrict__ T1)
{
    __shared__ cplx Ws[64];
    int bc = blockIdx.x >> 4, pc = blockIdx.x & 15;
    int tid = threadIdx.x;
    if (tid < 64) { float sn, cs; sincosf(-TWO_PI * tid / 64.f, &sn, &cs); Ws[tid] = make_float2(cs, sn); }
    __syncthreads();
    float mean = accH[bc * 2] * (1.f / 4096.f);
    float var  = accH[bc * 2 + 1] * (1.f / 4096.f) - mean * mean;
    float rstd = rsqrtf(var + 1e-5f);
    int j = tid & 63, pl = tid >> 6, p = pc * 4 + pl;
    const float* hb = h + bc * 4096 + j;
    float ax = 0.f, ay = 0.f;
    #pragma unroll 8
    for (int i = 0; i < 64; ++i) {
        float v = hb[i * 64];
        cplx w = Ws[(p * i) & 63];       // p wave-uniform -> broadcast
        ax += v * w.x; ay += v * w.y;
    }
    if (p == 0) ax -= 64.f * mean;
    T1[bc * 4096 + p * 64 + j] = make_float2(ax * rstd, ay * rstd);
}

// ---- K2: fft-stage-B (rotation recurrence, no twiddle table) ----------------
__global__ __launch_bounds__(256) void k2_fftB(
    const cplx* __restrict__ T1, cplx* __restrict__ alpha, cplx* __restrict__ alphaT)
{
    __shared__ cplx T1s[256];
    int bc = blockIdx.x >> 4, pc = blockIdx.x & 15;
    int tid = threadIdx.x;
    T1s[tid] = T1[bc * 4096 + pc * 256 + tid];
    __syncthreads();
    int q = tid & 63, pl = tid >> 6, p = pc * 4 + pl;
    float c1, s1; sincosf(-TWO_PI * (float)q * (1.f / 64.f), &s1, &c1);
    float wx = 1.f, wy = 0.f;
    float ax = 0.f, ay = 0.f;
    #pragma unroll 8
    for (int j = 0; j < 64; ++j) {
        cplx t = T1s[pl * 64 + j];       // pl,j wave-uniform -> broadcast
        ax += t.x * wx - t.y * wy;
        ay += t.x * wy + t.y * wx;
        float nwx = wx * c1 - wy * s1;
        wy = wx * s1 + wy * c1; wx = nwx;
    }
    cplx v = make_float2(ax, ay);
    alpha [bc * 4096 + p * 64 + q] = v;
    alphaT[(p * 64 + q) * 64 + bc] = v;
}

// ---- K3: fused G+r1 per (o,x): G[i][k]=sum_q Cq*Bq; r1[b,k]=sum_i a[b,i]*G --
__global__ __launch_bounds__(64) void k3_r1(
    const cplx* __restrict__ alphaT, const cplx* __restrict__ Cq,
    const cplx* __restrict__ Bq, cplx* __restrict__ r1)
{
    __shared__ cplx Cqs[1280], Bqs[1280], Gs[256], as[64];
    int ox = blockIdx.x; int o = ox >> 6, xx = ox & 63;
    int t = threadIdx.x;
    for (int m = 0; m < 20; ++m) {
        Cqs[m * 64 + t] = Cq[o * 1280 + m * 64 + t];
        Bqs[m * 64 + t] = Bq[xx * 1280 + m * 64 + t];
    }
    as[t] = alphaT[ox * 64 + t];
    __syncthreads();
    for (int m = 0; m < 4; ++m) {
        int e = m * 64 + t; int i = e >> 4, k = e & 15;
        float gx = 0.f, gy = 0.f;
        for (int q = 0; q < 5; ++q) cmac(gx, gy, Cqs[i * 80 + k * 5 + q], Bqs[i * 80 + k * 5 + q]);
        Gs[e] = make_float2(gx, gy);
    }
    __syncthreads();
    int b = t >> 4, k = t & 15;
    float ax = 0.f, ay = 0.f;
    for (int i = 0; i < 16; ++i) cmac(ax, ay, as[b * 16 + i], Gs[i * 16 + k]);
    r1[t * 4096 + ox] = make_float2(ax, ay);
}

// ---- K4: inner1[bi][o][k][q] = sum_x alpha[bi][o][x] * Bq[x][i][k][q] -------
__global__ __launch_bounds__(256) void k4_inner1(
    const cplx* __restrict__ alpha, const cplx* __restrict__ Bq,
    cplx* __restrict__ inner1)
{
    int idx = blockIdx.x * 256 + threadIdx.x;      // bi*5120 + o*80 + kq
    int kq = idx % 80; int r = idx / 80; int o = r & 63; int bi = r >> 6; int i = bi & 15;
    const cplx* arow = alpha + bi * 4096 + o * 64;
    const cplx* bcol = Bq + i * 80 + kq;
    float ax = 0.f, ay = 0.f;
    #pragma unroll 4
    for (int x = 0; x < 64; ++x) cmac(ax, ay, arow[x], bcol[x * 1280]);
    inner1[idx] = make_float2(ax, ay);
}

// ---- K5: r2[b][k][p][q], 4 waves/block (i split), LDS cross-wave reduce -----
__global__ __launch_bounds__(256) void k5_r2(
    const cplx* __restrict__ A, const cplx* __restrict__ inner1,
    const float* __restrict__ resr, const float* __restrict__ resi,
    cplx* __restrict__ r2)
{
    __shared__ cplx red[4][20];
    int bk = blockIdx.x; int b = bk >> 4, k = bk & 15;
    int o = threadIdx.x & 63, ig = threadIdx.x >> 6;
    float accx[4][5] = {}, accy[4][5] = {};
    for (int ii = 0; ii < 4; ++ii) {
        int i = ig * 4 + ii;
        cplx a[4];
        for (int p = 0; p < 4; ++p) a[p] = A[((o * 16 + i) * 16 + k) * 4 + p];
        cplx in[5];
        for (int q = 0; q < 5; ++q) in[q] = inner1[(b * 16 + i) * 5120 + o * 80 + k * 5 + q];
        int rb = (i * 16 + k) * 20;
        for (int p = 0; p < 4; ++p)
            for (int q = 0; q < 5; ++q) {
                float tx = a[p].x * in[q].x - a[p].y * in[q].y;
                float ty = a[p].x * in[q].y + a[p].y * in[q].x;
                float rr = resr[rb + p * 5 + q], ri = resi[rb + p * 5 + q];
                accx[p][q] += rr * tx - ri * ty;
                accy[p][q] += rr * ty + ri * tx;
            }
    }
    for (int m = 32; m; m >>= 1)
        for (int p = 0; p < 4; ++p)
            for (int q = 0; q < 5; ++q) {
                accx[p][q] += __shfl_xor(accx[p][q], m, 64);
                accy[p][q] += __shfl_xor(accy[p][q], m, 64);
            }
    if (o == 0)
        for (int p = 0; p < 4; ++p)
            for (int q = 0; q < 5; ++q)
                red[ig][p * 5 + q] = make_float2(accx[p][q], accy[p][q]);
    __syncthreads();
    if (threadIdx.x < 20) {
        float sx = 0.f, sy = 0.f;
        for (int g = 0; g < 4; ++g) { sx += red[g][threadIdx.x].x; sy += red[g][threadIdx.x].y; }
        r2[bk * 20 + threadIdx.x] = make_float2(sx, sy);
    }
}

// ---- K7: ifft-stage-A: T2[z][j] = sum_o r1[o][j]*Wp^(z*o) -------------------
__global__ __launch_bounds__(256) void k7_ifftA(
    const cplx* __restrict__ r1, cplx* __restrict__ T2)
{
    __shared__ cplx Ws[64];
    int bk = blockIdx.x >> 4, zc = blockIdx.x & 15;
    int tid = threadIdx.x;
    if (tid < 64) { float sn, cs; sincosf(TWO_PI * tid / 64.f, &sn, &cs); Ws[tid] = make_float2(cs, sn); }
    __syncthreads();
    int j = tid & 63, z = zc * 4 + (tid >> 6);
    const cplx* rr = r1 + bk * 4096 + j;
    float ax = 0.f, ay = 0.f;
    #pragma unroll 4
    for (int o = 0; o < 64; ++o) cmac(ax, ay, rr[o * 64], Ws[(z * o) & 63]);
    T2[bk * 4096 + z * 64 + j] = make_float2(ax, ay);
}

// ---- K8b: sp = ifftB(T2) + Re(V*e2), V computed in-block from r2,e1 ---------
// block = (bc, zc): 4 z-rows x 64 xx. Everything LDS-staged; rotation twiddles.
__global__ __launch_bounds__(256) void k8b_sp(
    const cplx* __restrict__ T2, const cplx* __restrict__ r2,
    const cplx* __restrict__ e1, const cplx* __restrict__ e2,
    float* __restrict__ sp, float* __restrict__ accS)
{
    __shared__ cplx Es[5120];            // e2 slice for ch: [bb][q][xx]
    __shared__ cplx Vs[320];             // [bq][zl]
    __shared__ cplx T2s[256];            // 4 rows x 64
    int bc = blockIdx.x >> 4, zc = blockIdx.x & 15;
    int b = bc >> 4, ch = bc & 15;
    int tid = threadIdx.x;
    // stage e2 slice (16 chunks of 320 at stride 5120 in source)
    for (int t = 0; t < 20; ++t) {
        int f = t * 256 + tid;
        int bb = f / 320, r = f - bb * 320;
        Es[f] = e2[(bb * 16 + ch) * 320 + r];
    }
    // stage T2 rows
    T2s[tid] = T2[bc * 4096 + zc * 256 + tid];
    // compute V slice: Vs[bq*4+zl] = sum_p r2[(b*16+bb)*20+p*5+q] * e1[((bb*16+ch)*4+p)*64+z]
    for (int e = tid; e < 320; e += 256) {
        int bq = e >> 2, zl = e & 3;
        int bb = bq / 5, q = bq - bb * 5;
        int z = zc * 4 + zl;
        float vx = 0.f, vy = 0.f;
        for (int p = 0; p < 4; ++p)
            cmac(vx, vy, r2[(b * 16 + bb) * 20 + p * 5 + q],
                         e1[((bb * 16 + ch) * 4 + p) * 64 + z]);
        Vs[e] = make_float2(vx, vy);
    }
    __syncthreads();
    int zl = tid >> 6, xx = tid & 63;
    // ifft stage B via rotation recurrence: sum_j T2s[zl][j] * W^(xx*j), W=e^{+i*2pi/64}
    float c1, s1; sincosf(TWO_PI * (float)xx * (1.f / 64.f), &s1, &c1);
    float wx = 1.f, wy = 0.f;
    float acc = 0.f;
    const cplx* trow = &T2s[zl * 64];
    #pragma unroll 8
    for (int j = 0; j < 64; ++j) {
        cplx t = trow[j];                // broadcast within wave
        acc += t.x * wx - t.y * wy;
        float nwx = wx * c1 - wy * s1;
        wy = wx * s1 + wy * c1; wx = nwx;
    }
    // V*e2 term
    #pragma unroll 5
    for (int bq = 0; bq < 80; ++bq) {
        cplx vv = Vs[bq * 4 + zl];       // broadcast within wave
        cplx ee = Es[bq * 64 + xx];      // lane-consecutive
        acc += vv.x * ee.x - vv.y * ee.y;
    }
    float val = acc * (1.f / 4096.f);
    sp[bc * 4096 + zc * 256 + tid] = val;
    float s = val, s2 = val * val;
    for (int m = 32; m; m >>= 1) {
        s  += __shfl_xor(s,  m, 64);
        s2 += __shfl_xor(s2, m, 64);
    }
    if ((tid & 63) == 0) {
        atomicAdd(&accS[bc * 2],     s);
        atomicAdd(&accS[bc * 2 + 1], s2);
    }
}

// ---- K9: out = fc2( sin( fc1( inorm(sp) + w0*h + w0_b ) ) ) -----------------
__global__ __launch_bounds__(256) void k9_final(
    const float* __restrict__ sp, const float* __restrict__ accS,
    const float* __restrict__ h,
    const float* __restrict__ w0_w, const float* __restrict__ w0_b,
    const float* __restrict__ fc1_w, const float* __restrict__ fc1_b,
    const float* __restrict__ fc2_w, const float* __restrict__ fc2_b,
    float* __restrict__ out)
{
    __shared__ float w1s[128 * 16], b1s[128], w2s[128], w0s[256], w0bs[16];
    __shared__ float mvm[16], mvr[16];
    int tid = threadIdx.x;
    int b = blockIdx.x >> 4;            // 16 blocks per batch
    for (int t = 0; t < 8; ++t) w1s[t * 256 + tid] = fc1_w[t * 256 + tid];
    if (tid < 128) { b1s[tid] = fc1_b[tid]; w2s[tid] = fc2_w[tid]; }
    w0s[tid] = w0_w[tid & 255];
    if (tid < 16) {
        w0bs[tid] = w0_b[tid];
        float mean = accS[(b * 16 + tid) * 2] * (1.f / 4096.f);
        float var  = accS[(b * 16 + tid) * 2 + 1] * (1.f / 4096.f) - mean * mean;
        mvm[tid] = mean;
        mvr[tid] = rsqrtf(var + 1e-5f);
    }
    float b2 = fc2_b[0];
    __syncthreads();
    int pix = blockIdx.x * 256 + tid;    // 0..16383
    int rem = pix & 4095;
    float hv[16], tv[16];
    for (int c = 0; c < 16; ++c) {
        hv[c] = h[(b * 16 + c) * 4096 + rem];
        tv[c] = (sp[(b * 16 + c) * 4096 + rem] - mvm[c]) * mvr[c];
    }
    for (int k = 0; k < 16; ++k) {
        float a = w0bs[k];
        for (int c = 0; c < 16; ++c) a += w0s[k * 16 + c] * hv[c];
        tv[k] += a;
    }
    float acc = b2;
    for (int n = 0; n < 128; ++n) {
        float s1 = b1s[n];
        for (int k2 = 0; k2 < 16; ++k2) s1 += w1s[n * 16 + k2] * tv[k2];
        acc += w2s[n] * sinf(s1);
    }
    out[pix] = acc;
}

extern "C" void kernel_launch(void* const* d_in, const int* in_sizes, int n_in,
                              void* d_out, int out_size, void* d_ws, size_t ws_size,
                              hipStream_t stream)
{
    const float* x     = (const float*)d_in[0];
    const float* fc0_w = (const float*)d_in[1];
    const float* fc0_b = (const float*)d_in[2];
    const float* p1r   = (const float*)d_in[3];
    const float* p1i   = (const float*)d_in[4];
    const float* p2r   = (const float*)d_in[5];
    const float* p2i   = (const float*)d_in[6];
    const float* resr  = (const float*)d_in[7];
    const float* resi  = (const float*)d_in[8];
    const float* w0_w  = (const float*)d_in[9];
    const float* w0_b  = (const float*)d_in[10];
    const float* fc1_w = (const float*)d_in[11];
    const float* fc1_b = (const float*)d_in[12];
    const float* fc2_w = (const float*)d_in[13];
    const float* fc2_b = (const float*)d_in[14];
    const float* t_grid= (const float*)d_in[15];
    const float* x_grid= (const float*)d_in[16];
    float* out = (float*)d_out;

    float* ws = (float*)d_ws;
    size_t off = 0;
    float* h      = ws + off; off += 262144;            // (64,4096)
    cplx*  T1     = (cplx*)(ws + off); off += 524288;   // (64,4096) c
    cplx*  alpha  = (cplx*)(ws + off); off += 524288;   // [bi][o][x] c
    cplx*  alphaT = (cplx*)(ws + off); off += 524288;   // [ox][bi] c
    cplx*  A      = (cplx*)(ws + off); off += 131072;   // (64,16,16,4) c
    cplx*  Bq     = (cplx*)(ws + off); off += 163840;   // (64,16,16,5) c
    cplx*  Cq     = (cplx*)(ws + off); off += 163840;   // (64,16,16,5) c
    cplx*  e1     = (cplx*)(ws + off); off += 131072;   // (16,16,4,64) c
    cplx*  e2     = (cplx*)(ws + off); off += 163840;   // (16,16,5,64) c
    cplx*  r1     = (cplx*)(ws + off); off += 524288;   // [bk][o][x] c
    cplx*  inner1 = (cplx*)(ws + off); off += 655360;   // [bi][o][k][q] c
    cplx*  r2     = (cplx*)(ws + off); off += 2560;     // (4,16,4,5) c
    cplx*  T2     = (cplx*)(ws + off); off += 524288;   // [bk][z][j] c
    float* sp     = ws + off; off += 262144;
    float* accum  = ws + off; off += 256;               // accH[128] + accS[128]
    float* accH = accum, *accS = accum + 128;
    (void)ws_size; (void)n_in; (void)in_sizes; (void)out_size;

    hipMemsetAsync(accum, 0, 256 * sizeof(float), stream);

    k_pre<<<2496, 256, 0, stream>>>(x, fc0_w, fc0_b, p1r, p1i, p2r, p2i, resr, resi,
                                    t_grid, x_grid, A, Bq, Cq, e1, e2, h, accH);
    k_fftA<<<1024, 256, 0, stream>>>(h, accH, T1);
    k2_fftB<<<1024, 256, 0, stream>>>(T1, alpha, alphaT);
    k3_r1<<<4096, 64, 0, stream>>>(alphaT, Cq, Bq, r1);
    k4_inner1<<<1280, 256, 0, stream>>>(alpha, Bq, inner1);
    k5_r2<<<64, 256, 0, stream>>>(A, inner1, resr, resi, r2);
    k7_ifftA<<<1024, 256, 0, stream>>>(r1, T2);
    k8b_sp<<<1024, 256, 0, stream>>>(T2, r2, e1, e2, sp, accS);
    k9_final<<<64, 256, 0, stream>>>(sp, accS, h, w0_w, w0_b, fc1_w, fc1_b, fc2_w, fc2_b, out);
}

// Round 7
// 202.453 us; speedup vs baseline: 1.2920x; 1.2426x over previous
//
#include <hip/hip_runtime.h>

typedef float2 cplx;

constexpr float TWO_PI = 6.28318530717958647692f;

__device__ inline void cmac(float& ax, float& ay, cplx a, cplx b) {
    ax += a.x * b.x - a.y * b.y;
    ay += a.x * b.y + a.y * b.x;
}

// ---- K_pre: A, Bq, Cq, e1, e2, h (+ per-wave mean/var partials of h) --------
__global__ __launch_bounds__(256) void k_pre(
    const float* __restrict__ x, const float* __restrict__ fc0_w,
    const float* __restrict__ fc0_b,
    const float* __restrict__ p1r, const float* __restrict__ p1i,
    const float* __restrict__ p2r, const float* __restrict__ p2i,
    const float* __restrict__ resr, const float* __restrict__ resi,
    const float* __restrict__ t_grid, const float* __restrict__ x_grid,
    cplx* __restrict__ A, cplx* __restrict__ Bq, cplx* __restrict__ Cq,
    cplx* __restrict__ e1, cplx* __restrict__ e2,
    float* __restrict__ h, float* __restrict__ accH2)
{
    int idx = blockIdx.x * 256 + threadIdx.x;
    float dty = x_grid[1] - x_grid[0];
    float dtx = t_grid[1] - t_grid[0];
    const int NA = 65536, NBQ = 81920, NCQ = 81920, NE1 = 65536, NE2 = 81920;
    if (idx < NA) {
        int p = idx & 3, k = (idx >> 2) & 15, i = (idx >> 6) & 15, o = idx >> 10;
        int kf = (o < 32) ? o : o - 64;
        float om = TWO_PI * (float)kf / (64.f * dty);
        float dr = -p1r[(i * 16 + k) * 4 + p], di = om - p1i[(i * 16 + k) * 4 + p];
        float inv = 1.f / (dr * dr + di * di);
        A[idx] = make_float2(dr * inv, -di * inv);
        return;
    }
    idx -= NA;
    if (idx < NBQ) {
        int q = idx % 5, k = (idx / 5) & 15, i = (idx / 80) & 15, xx = idx / 1280;
        int kf = (xx < 32) ? xx : xx - 64;
        float om = TWO_PI * (float)kf / (64.f * dtx);
        float dr = -p2r[(i * 16 + k) * 5 + q], di = om - p2i[(i * 16 + k) * 5 + q];
        float inv = 1.f / (dr * dr + di * di);
        Bq[idx] = make_float2(dr * inv, -di * inv);
        return;
    }
    idx -= NBQ;
    if (idx < NCQ) {
        int q = idx % 5, k = (idx / 5) & 15, i = (idx / 80) & 15, o = idx / 1280;
        int kf = (o < 32) ? o : o - 64;
        float om = TWO_PI * (float)kf / (64.f * dty);
        float cx = 0.f, cy = 0.f;
        for (int p = 0; p < 4; ++p) {
            float dr = -p1r[(i * 16 + k) * 4 + p], di = om - p1i[(i * 16 + k) * 4 + p];
            float inv = 1.f / (dr * dr + di * di);
            float axr = dr * inv, axi = -di * inv;
            float rr = resr[((i * 16 + k) * 4 + p) * 5 + q];
            float ri = resi[((i * 16 + k) * 4 + p) * 5 + q];
            cx += rr * axr - ri * axi;
            cy += rr * axi + ri * axr;
        }
        Cq[idx] = make_float2(cx, cy);
        return;
    }
    idx -= NCQ;
    if (idx < NE1) {
        int z = idx & 63, w = idx >> 6;
        float t = x_grid[z];
        float m = expf(p1r[w] * t);
        float sn, cs; sincosf(p1i[w] * t, &sn, &cs);
        e1[idx] = make_float2(m * cs, m * sn);
        return;
    }
    idx -= NE1;
    if (idx < NE2) {
        int xx = idx & 63, w = idx >> 6;
        float t = t_grid[xx];
        float m = expf(p2r[w] * t);
        float sn, cs; sincosf(p2i[w] * t, &sn, &cs);
        e2[idx] = make_float2(m * cs, m * sn);
        return;
    }
    idx -= NE2;
    {   // h = fc0(x,gx,gy) + per-wave mean/var partials (NO atomics)
        int bc = idx >> 12, pix = idx & 4095;
        int b = bc >> 4, c = bc & 15;
        int z = pix >> 6, xx = pix & 63;
        const float inv63 = 1.f / 63.f;
        float v = fc0_w[c * 3] * x[b * 4096 + pix]
                + fc0_w[c * 3 + 1] * (z * inv63)
                + fc0_w[c * 3 + 2] * (xx * inv63) + fc0_b[c];
        h[idx] = v;
        float s = v, s2 = v * v;
        for (int m = 32; m; m >>= 1) {
            s  += __shfl_xor(s,  m, 64);
            s2 += __shfl_xor(s2, m, 64);
        }
        if ((threadIdx.x & 63) == 0) {
            int widx = pix >> 6;              // 0..63, wave-unique per bc
            accH2[bc * 128 + widx * 2]     = s;
            accH2[bc * 128 + widx * 2 + 1] = s2;
        }
    }
}

// ---- K_fftA: T1[p][j] = rstd*(sum_i h[i][j]*W^(pi) - 64*mean*(p==0)) --------
__global__ __launch_bounds__(256) void k_fftA(
    const float* __restrict__ h, const float* __restrict__ accH2,
    cplx* __restrict__ T1)
{
    __shared__ cplx Ws[64];
    __shared__ float mv[2];
    int bc = blockIdx.x >> 4, pc = blockIdx.x & 15;
    int tid = threadIdx.x;
    if (tid < 64) { float sn, cs; sincosf(-TWO_PI * tid / 64.f, &sn, &cs); Ws[tid] = make_float2(cs, sn); }
    if (tid >= 64 && tid < 128) {
        int l = tid - 64;
        float s  = accH2[bc * 128 + l * 2];
        float s2 = accH2[bc * 128 + l * 2 + 1];
        for (int m = 32; m; m >>= 1) { s += __shfl_xor(s, m, 64); s2 += __shfl_xor(s2, m, 64); }
        if (l == 0) {
            float mean = s * (1.f / 4096.f);
            float var  = s2 * (1.f / 4096.f) - mean * mean;
            mv[0] = mean; mv[1] = rsqrtf(var + 1e-5f);
        }
    }
    __syncthreads();
    float mean = mv[0], rstd = mv[1];
    int j = tid & 63, pl = tid >> 6, p = pc * 4 + pl;
    const float* hb = h + bc * 4096 + j;
    float ax = 0.f, ay = 0.f;
    #pragma unroll 8
    for (int i = 0; i < 64; ++i) {
        float v = hb[i * 64];
        cplx w = Ws[(p * i) & 63];       // p wave-uniform -> broadcast
        ax += v * w.x; ay += v * w.y;
    }
    if (p == 0) ax -= 64.f * mean;
    T1[bc * 4096 + p * 64 + j] = make_float2(ax * rstd, ay * rstd);
}

// ---- K2: fft-stage-B (rotation recurrence, no twiddle table) ----------------
__global__ __launch_bounds__(256) void k2_fftB(
    const cplx* __restrict__ T1, cplx* __restrict__ alpha, cplx* __restrict__ alphaT)
{
    __shared__ cplx T1s[256];
    int bc = blockIdx.x >> 4, pc = blockIdx.x & 15;
    int tid = threadIdx.x;
    T1s[tid] = T1[bc * 4096 + pc * 256 + tid];
    __syncthreads();
    int q = tid & 63, pl = tid >> 6, p = pc * 4 + pl;
    float c1, s1; sincosf(-TWO_PI * (float)q * (1.f / 64.f), &s1, &c1);
    float wx = 1.f, wy = 0.f;
    float ax = 0.f, ay = 0.f;
    #pragma unroll 8
    for (int j = 0; j < 64; ++j) {
        cplx t = T1s[pl * 64 + j];       // pl,j wave-uniform -> broadcast
        ax += t.x * wx - t.y * wy;
        ay += t.x * wy + t.y * wx;
        float nwx = wx * c1 - wy * s1;
        wy = wx * s1 + wy * c1; wx = nwx;
    }
    cplx v = make_float2(ax, ay);
    alpha [bc * 4096 + p * 64 + q] = v;
    alphaT[(p * 64 + q) * 64 + bc] = v;
}

// ---- K3: fused G+r1 per (o,x): G[i][k]=sum_q Cq*Bq; r1[b,k]=sum_i a[b,i]*G --
__global__ __launch_bounds__(64) void k3_r1(
    const cplx* __restrict__ alphaT, const cplx* __restrict__ Cq,
    const cplx* __restrict__ Bq, cplx* __restrict__ r1)
{
    __shared__ cplx Cqs[1280], Bqs[1280], Gs[256], as[64];
    int ox = blockIdx.x; int o = ox >> 6, xx = ox & 63;
    int t = threadIdx.x;
    for (int m = 0; m < 20; ++m) {
        Cqs[m * 64 + t] = Cq[o * 1280 + m * 64 + t];
        Bqs[m * 64 + t] = Bq[xx * 1280 + m * 64 + t];
    }
    as[t] = alphaT[ox * 64 + t];
    __syncthreads();
    for (int m = 0; m < 4; ++m) {
        int e = m * 64 + t; int i = e >> 4, k = e & 15;
        float gx = 0.f, gy = 0.f;
        for (int q = 0; q < 5; ++q) cmac(gx, gy, Cqs[i * 80 + k * 5 + q], Bqs[i * 80 + k * 5 + q]);
        Gs[e] = make_float2(gx, gy);
    }
    __syncthreads();
    int b = t >> 4, k = t & 15;
    float ax = 0.f, ay = 0.f;
    for (int i = 0; i < 16; ++i) cmac(ax, ay, as[b * 16 + i], Gs[i * 16 + k]);
    r1[t * 4096 + ox] = make_float2(ax, ay);
}

// ---- K4: inner1[bi][o][k][q] = sum_x alpha[bi][o][x] * Bq[x][i][k][q] -------
__global__ __launch_bounds__(256) void k4_inner1(
    const cplx* __restrict__ alpha, const cplx* __restrict__ Bq,
    cplx* __restrict__ inner1)
{
    int idx = blockIdx.x * 256 + threadIdx.x;      // bi*5120 + o*80 + kq
    int kq = idx % 80; int r = idx / 80; int o = r & 63; int bi = r >> 6; int i = bi & 15;
    const cplx* arow = alpha + bi * 4096 + o * 64;
    const cplx* bcol = Bq + i * 80 + kq;
    float ax = 0.f, ay = 0.f;
    #pragma unroll 4
    for (int x = 0; x < 64; ++x) cmac(ax, ay, arow[x], bcol[x * 1280]);
    inner1[idx] = make_float2(ax, ay);
}

// ---- K5: r2[b][k][p][q], 4 waves/block (i split), LDS cross-wave reduce -----
__global__ __launch_bounds__(256) void k5_r2(
    const cplx* __restrict__ A, const cplx* __restrict__ inner1,
    const float* __restrict__ resr, const float* __restrict__ resi,
    cplx* __restrict__ r2)
{
    __shared__ cplx red[4][20];
    int bk = blockIdx.x; int b = bk >> 4, k = bk & 15;
    int o = threadIdx.x & 63, ig = threadIdx.x >> 6;
    float accx[4][5] = {}, accy[4][5] = {};
    for (int ii = 0; ii < 4; ++ii) {
        int i = ig * 4 + ii;
        cplx a[4];
        for (int p = 0; p < 4; ++p) a[p] = A[((o * 16 + i) * 16 + k) * 4 + p];
        cplx in[5];
        for (int q = 0; q < 5; ++q) in[q] = inner1[(b * 16 + i) * 5120 + o * 80 + k * 5 + q];
        int rb = (i * 16 + k) * 20;
        for (int p = 0; p < 4; ++p)
            for (int q = 0; q < 5; ++q) {
                float tx = a[p].x * in[q].x - a[p].y * in[q].y;
                float ty = a[p].x * in[q].y + a[p].y * in[q].x;
                float rr = resr[rb + p * 5 + q], ri = resi[rb + p * 5 + q];
                accx[p][q] += rr * tx - ri * ty;
                accy[p][q] += rr * ty + ri * tx;
            }
    }
    for (int m = 32; m; m >>= 1)
        for (int p = 0; p < 4; ++p)
            for (int q = 0; q < 5; ++q) {
                accx[p][q] += __shfl_xor(accx[p][q], m, 64);
                accy[p][q] += __shfl_xor(accy[p][q], m, 64);
            }
    if (o == 0)
        for (int p = 0; p < 4; ++p)
            for (int q = 0; q < 5; ++q)
                red[ig][p * 5 + q] = make_float2(accx[p][q], accy[p][q]);
    __syncthreads();
    if (threadIdx.x < 20) {
        float sx = 0.f, sy = 0.f;
        for (int g = 0; g < 4; ++g) { sx += red[g][threadIdx.x].x; sy += red[g][threadIdx.x].y; }
        r2[bk * 20 + threadIdx.x] = make_float2(sx, sy);
    }
}

// ---- K7: ifft-stage-A: T2[z][j] = sum_o r1[o][j]*Wp^(z*o) -------------------
__global__ __launch_bounds__(256) void k7_ifftA(
    const cplx* __restrict__ r1, cplx* __restrict__ T2)
{
    __shared__ cplx Ws[64];
    int bk = blockIdx.x >> 4, zc = blockIdx.x & 15;
    int tid = threadIdx.x;
    if (tid < 64) { float sn, cs; sincosf(TWO_PI * tid / 64.f, &sn, &cs); Ws[tid] = make_float2(cs, sn); }
    __syncthreads();
    int j = tid & 63, z = zc * 4 + (tid >> 6);
    const cplx* rr = r1 + bk * 4096 + j;
    float ax = 0.f, ay = 0.f;
    #pragma unroll 4
    for (int o = 0; o < 64; ++o) cmac(ax, ay, rr[o * 64], Ws[(z * o) & 63]);
    T2[bk * 4096 + z * 64 + j] = make_float2(ax, ay);
}

// ---- K8c: sp = ifftB(T2) + Re(V*e2); V in-block; per-wave stat partials -----
__global__ __launch_bounds__(256) void k8c_sp(
    const cplx* __restrict__ T2, const cplx* __restrict__ r2,
    const cplx* __restrict__ e1, const cplx* __restrict__ e2,
    float* __restrict__ sp, float* __restrict__ accS2)
{
    __shared__ cplx Vs[320];             // [bq][zl]
    __shared__ cplx T2s[256];            // 4 rows x 64
    int bc = blockIdx.x >> 4, zc = blockIdx.x & 15;
    int b = bc >> 4, ch = bc & 15;
    int tid = threadIdx.x;
    T2s[tid] = T2[bc * 4096 + zc * 256 + tid];
    // V slice: Vs[bq*4+zl] = sum_p r2[(b*16+bb)*20+p*5+q] * e1[((bb*16+ch)*4+p)*64+z]
    for (int e = tid; e < 320; e += 256) {
        int bq = e >> 2, zl = e & 3;
        int bb = bq / 5, q = bq - bb * 5;
        int z = zc * 4 + zl;
        float vx = 0.f, vy = 0.f;
        for (int p = 0; p < 4; ++p)
            cmac(vx, vy, r2[(b * 16 + bb) * 20 + p * 5 + q],
                         e1[((bb * 16 + ch) * 4 + p) * 64 + z]);
        Vs[e] = make_float2(vx, vy);
    }
    __syncthreads();
    int zl = tid >> 6, xx = tid & 63;
    // ifft stage B via rotation recurrence
    float c1, s1; sincosf(TWO_PI * (float)xx * (1.f / 64.f), &s1, &c1);
    float wx = 1.f, wy = 0.f;
    float acc = 0.f;
    const cplx* trow = &T2s[zl * 64];
    #pragma unroll 8
    for (int j = 0; j < 64; ++j) {
        cplx t = trow[j];                // broadcast within wave
        acc += t.x * wx - t.y * wy;
        float nwx = wx * c1 - wy * s1;
        wy = wx * s1 + wy * c1; wx = nwx;
    }
    // V*e2 term (e2 direct from L2; loads independent)
    const cplx* eb = e2 + ch * 320 + xx;
    #pragma unroll 4
    for (int bb = 0; bb < 16; ++bb)
        for (int q = 0; q < 5; ++q) {
            cplx vv = Vs[(bb * 5 + q) * 4 + zl];   // broadcast within wave
            cplx ee = eb[bb * 5120 + q * 64];      // lane-consecutive, L2
            acc += vv.x * ee.x - vv.y * ee.y;
        }
    float val = acc * (1.f / 4096.f);
    sp[bc * 4096 + zc * 256 + tid] = val;
    float s = val, s2 = val * val;
    for (int m = 32; m; m >>= 1) {
        s  += __shfl_xor(s,  m, 64);
        s2 += __shfl_xor(s2, m, 64);
    }
    if ((tid & 63) == 0) {
        int widx = zc * 4 + (tid >> 6);   // 0..63, wave-unique per bc
        accS2[bc * 128 + widx * 2]     = s;
        accS2[bc * 128 + widx * 2 + 1] = s2;
    }
}

// ---- K9: out = fc2( sin( fc1( inorm(sp) + w0*h + w0_b ) ) ) -----------------
__global__ __launch_bounds__(256) void k9_final(
    const float* __restrict__ sp, const float* __restrict__ accS2,
    const float* __restrict__ h,
    const float* __restrict__ w0_w, const float* __restrict__ w0_b,
    const float* __restrict__ fc1_w, const float* __restrict__ fc1_b,
    const float* __restrict__ fc2_w, const float* __restrict__ fc2_b,
    float* __restrict__ out)
{
    __shared__ float w1s[128 * 16], b1s[128], w2s[128], w0s[256], w0bs[16];
    __shared__ float mvm[16], mvr[16];
    int tid = threadIdx.x;
    int b = blockIdx.x >> 4;            // 16 blocks per batch
    for (int t = 0; t < 8; ++t) w1s[t * 256 + tid] = fc1_w[t * 256 + tid];
    if (tid < 128) { b1s[tid] = fc1_b[tid]; w2s[tid] = fc2_w[tid]; }
    w0s[tid] = w0_w[tid & 255];
    if (tid < 16) w0bs[tid] = w0_b[tid];
    // stats: 4 waves x 4 channels each, 64-lane shfl reduce of partials
    {
        int wv = tid >> 6, ln = tid & 63;
        for (int cc = 0; cc < 4; ++cc) {
            int c = wv * 4 + cc;
            float s  = accS2[(b * 16 + c) * 128 + ln * 2];
            float s2 = accS2[(b * 16 + c) * 128 + ln * 2 + 1];
            for (int m = 32; m; m >>= 1) { s += __shfl_xor(s, m, 64); s2 += __shfl_xor(s2, m, 64); }
            if (ln == 0) {
                float mean = s * (1.f / 4096.f);
                float var  = s2 * (1.f / 4096.f) - mean * mean;
                mvm[c] = mean; mvr[c] = rsqrtf(var + 1e-5f);
            }
        }
    }
    float b2 = fc2_b[0];
    __syncthreads();
    int pix = blockIdx.x * 256 + tid;    // 0..16383
    int rem = pix & 4095;
    float hv[16], tv[16];
    for (int c = 0; c < 16; ++c) {
        hv[c] = h[(b * 16 + c) * 4096 + rem];
        tv[c] = (sp[(b * 16 + c) * 4096 + rem] - mvm[c]) * mvr[c];
    }
    for (int k = 0; k < 16; ++k) {
        float a = w0bs[k];
        for (int c = 0; c < 16; ++c) a += w0s[k * 16 + c] * hv[c];
        tv[k] += a;
    }
    float acc = b2;
    for (int n = 0; n < 128; ++n) {
        float s1 = b1s[n];
        for (int k2 = 0; k2 < 16; ++k2) s1 += w1s[n * 16 + k2] * tv[k2];
        acc += w2s[n] * sinf(s1);
    }
    out[pix] = acc;
}

extern "C" void kernel_launch(void* const* d_in, const int* in_sizes, int n_in,
                              void* d_out, int out_size, void* d_ws, size_t ws_size,
                              hipStream_t stream)
{
    const float* x     = (const float*)d_in[0];
    const float* fc0_w = (const float*)d_in[1];
    const float* fc0_b = (const float*)d_in[2];
    const float* p1r   = (const float*)d_in[3];
    const float* p1i   = (const float*)d_in[4];
    const float* p2r   = (const float*)d_in[5];
    const float* p2i   = (const float*)d_in[6];
    const float* resr  = (const float*)d_in[7];
    const float* resi  = (const float*)d_in[8];
    const float* w0_w  = (const float*)d_in[9];
    const float* w0_b  = (const float*)d_in[10];
    const float* fc1_w = (const float*)d_in[11];
    const float* fc1_b = (const float*)d_in[12];
    const float* fc2_w = (const float*)d_in[13];
    const float* fc2_b = (const float*)d_in[14];
    const float* t_grid= (const float*)d_in[15];
    const float* x_grid= (const float*)d_in[16];
    float* out = (float*)d_out;

    float* ws = (float*)d_ws;
    size_t off = 0;
    float* h      = ws + off; off += 262144;            // (64,4096)
    cplx*  T1     = (cplx*)(ws + off); off += 524288;   // (64,4096) c
    cplx*  alpha  = (cplx*)(ws + off); off += 524288;   // [bi][o][x] c
    cplx*  alphaT = (cplx*)(ws + off); off += 524288;   // [ox][bi] c
    cplx*  A      = (cplx*)(ws + off); off += 131072;   // (64,16,16,4) c
    cplx*  Bq     = (cplx*)(ws + off); off += 163840;   // (64,16,16,5) c
    cplx*  Cq     = (cplx*)(ws + off); off += 163840;   // (64,16,16,5) c
    cplx*  e1     = (cplx*)(ws + off); off += 131072;   // (16,16,4,64) c
    cplx*  e2     = (cplx*)(ws + off); off += 163840;   // (16,16,5,64) c
    cplx*  r1     = (cplx*)(ws + off); off += 524288;   // [bk][o][x] c
    cplx*  inner1 = (cplx*)(ws + off); off += 655360;   // [bi][o][k][q] c
    cplx*  r2     = (cplx*)(ws + off); off += 2560;     // (4,16,4,5) c
    cplx*  T2     = (cplx*)(ws + off); off += 524288;   // [bk][z][j] c
    float* sp     = ws + off; off += 262144;
    float* accH2  = ws + off; off += 8192;              // [bc][64 waves][2]
    float* accS2  = ws + off; off += 8192;              // [bc][64 waves][2]
    (void)ws_size; (void)n_in; (void)in_sizes; (void)out_size;

    k_pre<<<2496, 256, 0, stream>>>(x, fc0_w, fc0_b, p1r, p1i, p2r, p2i, resr, resi,
                                    t_grid, x_grid, A, Bq, Cq, e1, e2, h, accH2);
    k_fftA<<<1024, 256, 0, stream>>>(h, accH2, T1);
    k2_fftB<<<1024, 256, 0, stream>>>(T1, alpha, alphaT);
    k3_r1<<<4096, 64, 0, stream>>>(alphaT, Cq, Bq, r1);
    k4_inner1<<<1280, 256, 0, stream>>>(alpha, Bq, inner1);
    k5_r2<<<64, 256, 0, stream>>>(A, inner1, resr, resi, r2);
    k7_ifftA<<<1024, 256, 0, stream>>>(r1, T2);
    k8c_sp<<<1024, 256, 0, stream>>>(T2, r2, e1, e2, sp, accS2);
    k9_final<<<64, 256, 0, stream>>>(sp, accS2, h, w0_w, w0_b, fc1_w, fc1_b, fc2_w, fc2_b, out);
}